// Round 5
// baseline (1651.814 us; speedup 1.0000x reference)
//
#include <hip/hip_runtime.h>
#include <stdint.h>

#define T_STEPS 4
#define NTOK    8192
#define DMODEL  1024
#define NEXP    8
#define EFF     512
#define BMT     128
#define CAPTOT  (2*NTOK + NEXP*BMT)   // 17408 assignment slots (regions padded to 128)

typedef __attribute__((ext_vector_type(8))) short bf8_t;   // 8 bf16 = one MFMA operand
typedef __attribute__((ext_vector_type(4))) float f32x4;   // MFMA accumulator

#define MFMA(a,b,c) __builtin_amdgcn_mfma_f32_16x16x32_bf16((a),(b),(c),0,0,0)

// ---------------- ws layout (bytes) ----------------
#define WS_TOK   128
#define WS_WGT   (WS_TOK + CAPTOT*4)
#define WS_SPK   (WS_WGT + CAPTOT*4)                  // bf16 spikes [t][CAPTOT][EFF]
#define SPK_SZ   ((size_t)4*CAPTOT*EFF*2)
#define WS_XH    (WS_SPK + SPK_SZ)
#define XPL_SZ   ((size_t)T_STEPS*NTOK*DMODEL*2)
#define WS_XM    (WS_XH + XPL_SZ)
#define WS_XL    (WS_XM + XPL_SZ)
#define WPL_SZ   ((size_t)NEXP*EFF*DMODEL*2)
#define WS_UH    (WS_XL + XPL_SZ)
#define WS_UM    (WS_UH + WPL_SZ)
#define WS_UL    (WS_UM + WPL_SZ)
#define WS_DH    (WS_UL + WPL_SZ)
#define WS_DM    (WS_DH + WPL_SZ)
#define WS_DL    (WS_DM + WPL_SZ)
// total ~309 MB

// ---------------- bf16 split helpers ----------------

__device__ __forceinline__ unsigned short bf16rn(float f) {
    unsigned u = __float_as_uint(f);
    unsigned r = u + 0x7fffu + ((u >> 16) & 1u);   // RNE
    return (unsigned short)(r >> 16);
}
__device__ __forceinline__ float bf2f(unsigned short h) {
    return __uint_as_float(((unsigned)h) << 16);
}
__device__ __forceinline__ unsigned pk(unsigned short a, unsigned short b) {
    return (unsigned)a | ((unsigned)b << 16);
}

// fp32 -> 3 bf16 limb planes, 8 elements per thread
__global__ __launch_bounds__(256)
void k_split3(const float* __restrict__ in, unsigned short* __restrict__ ph,
              unsigned short* __restrict__ pm, unsigned short* __restrict__ pl, int n8) {
    int i = blockIdx.x * blockDim.x + threadIdx.x;
    if (i >= n8) return;
    const float* src = in + (size_t)i * 8;
    float v[8];
    *(float4*)&v[0] = *(const float4*)(src + 0);
    *(float4*)&v[4] = *(const float4*)(src + 4);
    unsigned short h[8], m[8], l[8];
#pragma unroll
    for (int j = 0; j < 8; ++j) {
        unsigned short a = bf16rn(v[j]);
        float r1 = v[j] - bf2f(a);
        unsigned short b = bf16rn(r1);
        float r2 = r1 - bf2f(b);
        h[j] = a; m[j] = b; l[j] = bf16rn(r2);
    }
    *(uint4*)(ph + (size_t)i*8) = make_uint4(pk(h[0],h[1]), pk(h[2],h[3]), pk(h[4],h[5]), pk(h[6],h[7]));
    *(uint4*)(pm + (size_t)i*8) = make_uint4(pk(m[0],m[1]), pk(m[2],m[3]), pk(m[4],m[5]), pk(m[6],m[7]));
    *(uint4*)(pl + (size_t)i*8) = make_uint4(pk(l[0],l[1]), pk(l[2],l[3]), pk(l[4],l[5]), pk(l[6],l[7]));
}

// ---------------- routing ----------------

__global__ void k_count(const int* __restrict__ idx, int* __restrict__ counts) {
    int n = blockIdx.x * blockDim.x + threadIdx.x;
    if (n >= NTOK) return;
    int e0 = idx[2*n], e1 = idx[2*n+1];
    atomicAdd(&counts[e0], 1);
    if (e1 != e0) atomicAdd(&counts[e1], 1);
}

__global__ void k_prefix(const int* __restrict__ counts, int* __restrict__ offsets) {
    if (threadIdx.x == 0) {
        int o = 0;
        for (int e = 0; e < NEXP; ++e) {
            offsets[e] = o;
            o += (counts[e] + BMT - 1) / BMT * BMT;
        }
        offsets[NEXP] = o;
    }
}

__global__ void k_fill(const int* __restrict__ idx, const float* __restrict__ wts,
                       const int* __restrict__ offsets, int* __restrict__ cursors,
                       int* __restrict__ tok, float* __restrict__ wgt) {
    int n = blockIdx.x * blockDim.x + threadIdx.x;
    if (n >= NTOK) return;
    int e0 = idx[2*n], e1 = idx[2*n+1];
    float w0 = wts[2*n], w1 = wts[2*n+1];
    if (e0 == e1) w0 = __fadd_rn(w0, w1);
    int p0 = offsets[e0] + atomicAdd(&cursors[e0], 1);
    tok[p0] = n; wgt[p0] = w0;
    if (e1 != e0) {
        int p1 = offsets[e1] + atomicAdd(&cursors[e1], 1);
        tok[p1] = n; wgt[p1] = w1;
    }
}

// ---------------- up-proj: LDS-free 3x3-limb bf16 MFMA + fused LIF -> bf16 spikes ----------------
// Block 128x128, 4 waves in 2x2, wave-tile 64x64 (4x4 16x16 MFMA tiles).
// All operands loaded straight from limb planes to VGPRs (coalesced uint4), no LDS, no barriers.

__global__ __launch_bounds__(256, 2)
void k_up(const unsigned short* __restrict__ xh, const unsigned short* __restrict__ xm,
          const unsigned short* __restrict__ xl, const unsigned short* __restrict__ wh,
          const unsigned short* __restrict__ wm, const unsigned short* __restrict__ wl,
          const int* __restrict__ offsets, const int* __restrict__ tok,
          unsigned short* __restrict__ spk) {
    const int m0 = blockIdx.x * BMT;
    const int ft = blockIdx.y;
    if (m0 >= offsets[NEXP]) return;
    int e = 0;
    for (int i = 1; i < NEXP; ++i) if (m0 >= offsets[i]) e = i;

    const int lane = threadIdx.x & 63, wid = threadIdx.x >> 6;
    const int quad = lane >> 4, l16 = lane & 15;
    const int mw = (wid & 1) * 64, nw = (wid >> 1) * 64;

    unsigned aoff[4], boff[4];
#pragma unroll
    for (int mt = 0; mt < 4; ++mt)
        aoff[mt] = (unsigned)tok[m0 + mw + mt*16 + l16] * DMODEL + quad*8;
#pragma unroll
    for (int nt = 0; nt < 4; ++nt)
        boff[nt] = ((unsigned)e*EFF + ft*BMT + nw + nt*16 + l16) * DMODEL + quad*8;

    f32x4 mem[4][4];
#pragma unroll
    for (int i = 0; i < 4; ++i)
#pragma unroll
        for (int j = 0; j < 4; ++j) mem[i][j] = (f32x4){0.f,0.f,0.f,0.f};

    for (int t = 0; t < T_STEPS; ++t) {
        f32x4 acc[4][4];
#pragma unroll
        for (int i = 0; i < 4; ++i)
#pragma unroll
            for (int j = 0; j < 4; ++j) acc[i][j] = (f32x4){0.f,0.f,0.f,0.f};

        const unsigned xt = (unsigned)t * (NTOK * DMODEL);

        for (int kc = 0; kc < DMODEL; kc += 32) {
            bf8_t bh[4], bm[4], bl[4];
#pragma unroll
            for (int nt = 0; nt < 4; ++nt) {
                bh[nt] = *(const bf8_t*)(wh + boff[nt] + kc);
                bm[nt] = *(const bf8_t*)(wm + boff[nt] + kc);
                bl[nt] = *(const bf8_t*)(wl + boff[nt] + kc);
            }
#pragma unroll
            for (int mt = 0; mt < 4; ++mt) {
                bf8_t ah = *(const bf8_t*)(xh + xt + aoff[mt] + kc);
                bf8_t am = *(const bf8_t*)(xm + xt + aoff[mt] + kc);
                bf8_t al = *(const bf8_t*)(xl + xt + aoff[mt] + kc);
#pragma unroll
                for (int nt = 0; nt < 4; ++nt) {
                    f32x4 c = acc[mt][nt];
                    c = MFMA(ah, bh[nt], c);
                    c = MFMA(am, bh[nt], c);
                    c = MFMA(ah, bm[nt], c);
                    c = MFMA(am, bm[nt], c);
                    c = MFMA(al, bh[nt], c);
                    c = MFMA(ah, bl[nt], c);
                    acc[mt][nt] = c;
                }
            }
        }

        // fused LIF epilogue (C layout: row = quad*4+reg, col = l16)
#pragma unroll
        for (int mt = 0; mt < 4; ++mt)
#pragma unroll
            for (int nt = 0; nt < 4; ++nt)
#pragma unroll
                for (int reg = 0; reg < 4; ++reg) {
                    float mv = __fadd_rn(__fmul_rn(0.9f, mem[mt][nt][reg]), acc[mt][nt][reg]);
                    bool s = mv > 1.0f;
                    mem[mt][nt][reg] = __fsub_rn(mv, s ? 1.0f : 0.0f);
                    int row = m0 + mw + mt*16 + quad*4 + reg;
                    int col = ft*BMT + nw + nt*16 + l16;
                    spk[((size_t)t * CAPTOT + row) * EFF + col] = s ? 0x3F80u : 0u;
                }
    }
}

// ---------------- down-proj: exact bf16 spikes x 3-limb weights, LDS-free + fused LIF + scatter ----
// Block 128x128, wave-tile 64x64 (4x4 tiles), K=EFF in 32-chunks.

__global__ __launch_bounds__(256, 2)
void k_dn(const unsigned short* __restrict__ spk, const unsigned short* __restrict__ dh,
          const unsigned short* __restrict__ dm, const unsigned short* __restrict__ dl,
          const int* __restrict__ offsets, const int* __restrict__ tok,
          const float* __restrict__ wgt, float* __restrict__ out) {
    const int m0 = blockIdx.x * BMT;
    const int dt = blockIdx.y;
    if (m0 >= offsets[NEXP]) return;
    int e = 0;
    for (int i = 1; i < NEXP; ++i) if (m0 >= offsets[i]) e = i;

    const int lane = threadIdx.x & 63, wid = threadIdx.x >> 6;
    const int quad = lane >> 4, l16 = lane & 15;
    const int mw = (wid & 1) * 64, nw = (wid >> 1) * 64;

    unsigned aoff[4], boff[4];
#pragma unroll
    for (int mt = 0; mt < 4; ++mt)
        aoff[mt] = (unsigned)(m0 + mw + mt*16 + l16) * EFF + quad*8;
#pragma unroll
    for (int nt = 0; nt < 4; ++nt)
        boff[nt] = ((unsigned)e*DMODEL + dt*BMT + nw + nt*16 + l16) * EFF + quad*8;

    int   rn[4][4];
    float rw[4][4];
#pragma unroll
    for (int mt = 0; mt < 4; ++mt)
#pragma unroll
        for (int reg = 0; reg < 4; ++reg) {
            int rr = m0 + mw + mt*16 + quad*4 + reg;
            rn[mt][reg] = tok[rr];
            rw[mt][reg] = wgt[rr];
        }

    f32x4 mem[4][4];
#pragma unroll
    for (int i = 0; i < 4; ++i)
#pragma unroll
        for (int j = 0; j < 4; ++j) mem[i][j] = (f32x4){0.f,0.f,0.f,0.f};

    for (int t = 0; t < T_STEPS; ++t) {
        f32x4 acc[4][4];
#pragma unroll
        for (int i = 0; i < 4; ++i)
#pragma unroll
            for (int j = 0; j < 4; ++j) acc[i][j] = (f32x4){0.f,0.f,0.f,0.f};

        const unsigned st = (unsigned)t * (CAPTOT * EFF);

        for (int kc = 0; kc < EFF; kc += 32) {
            bf8_t bh[4], bm[4], bl[4];
#pragma unroll
            for (int nt = 0; nt < 4; ++nt) {
                bh[nt] = *(const bf8_t*)(dh + boff[nt] + kc);
                bm[nt] = *(const bf8_t*)(dm + boff[nt] + kc);
                bl[nt] = *(const bf8_t*)(dl + boff[nt] + kc);
            }
#pragma unroll
            for (int mt = 0; mt < 4; ++mt) {
                bf8_t a = *(const bf8_t*)(spk + st + aoff[mt] + kc);
#pragma unroll
                for (int nt = 0; nt < 4; ++nt) {
                    f32x4 c = acc[mt][nt];
                    c = MFMA(a, bh[nt], c);
                    c = MFMA(a, bm[nt], c);
                    c = MFMA(a, bl[nt], c);
                    acc[mt][nt] = c;
                }
            }
        }

        // fused LIF + weighted sparse scatter (output spikes rare -> few atomics)
#pragma unroll
        for (int mt = 0; mt < 4; ++mt)
#pragma unroll
            for (int nt = 0; nt < 4; ++nt)
#pragma unroll
                for (int reg = 0; reg < 4; ++reg) {
                    float mv = __fadd_rn(__fmul_rn(0.9f, mem[mt][nt][reg]), acc[mt][nt][reg]);
                    bool s = mv > 1.0f;
                    mem[mt][nt][reg] = __fsub_rn(mv, s ? 1.0f : 0.0f);
                    float w = rw[mt][reg];
                    if (s && w != 0.0f) {
                        int col = dt*BMT + nw + nt*16 + l16;
                        atomicAdd(out + ((size_t)t * NTOK + rn[mt][reg]) * DMODEL + col, w);
                    }
                }
    }
}

// ---------------- launch ----------------

extern "C" void kernel_launch(void* const* d_in, const int* in_sizes, int n_in,
                              void* d_out, int out_size, void* d_ws, size_t ws_size,
                              hipStream_t stream) {
    const float* x      = (const float*)d_in[0];
    const int*   idx    = (const int*)  d_in[1];
    const float* wts    = (const float*)d_in[2];
    const float* up_w   = (const float*)d_in[3];
    const float* down_w = (const float*)d_in[4];
    float* out = (float*)d_out;

    char* ws = (char*)d_ws;
    int*   counts  = (int*)(ws + 0);
    int*   cursors = (int*)(ws + 32);
    int*   offsets = (int*)(ws + 64);
    int*   tok     = (int*)(ws + WS_TOK);
    float* wgt     = (float*)(ws + WS_WGT);
    unsigned short* spk = (unsigned short*)(ws + WS_SPK);
    unsigned short* xh = (unsigned short*)(ws + WS_XH);
    unsigned short* xm = (unsigned short*)(ws + WS_XM);
    unsigned short* xl = (unsigned short*)(ws + WS_XL);
    unsigned short* uh = (unsigned short*)(ws + WS_UH);
    unsigned short* um = (unsigned short*)(ws + WS_UM);
    unsigned short* ul = (unsigned short*)(ws + WS_UL);
    unsigned short* dh = (unsigned short*)(ws + WS_DH);
    unsigned short* dm = (unsigned short*)(ws + WS_DM);
    unsigned short* dl = (unsigned short*)(ws + WS_DL);
    // ws footprint: WS_DL + WPL_SZ ~= 309 MB

    hipMemsetAsync(ws, 0, WS_SPK, stream);                               // hdr + tok + wgt
    hipMemsetAsync(out, 0, (size_t)out_size * sizeof(float), stream);

    // presplit limb planes
    const int nx8 = T_STEPS*NTOK*DMODEL/8;   // 4194304
    const int nw8 = NEXP*EFF*DMODEL/8;       // 524288
    k_split3<<<nx8/256, 256, 0, stream>>>(x, xh, xm, xl, nx8);
    k_split3<<<nw8/256, 256, 0, stream>>>(up_w, uh, um, ul, nw8);
    k_split3<<<nw8/256, 256, 0, stream>>>(down_w, dh, dm, dl, nw8);

    // routing
    k_count <<<(NTOK + 255) / 256, 256, 0, stream>>>(idx, counts);
    k_prefix<<<1, 64, 0, stream>>>(counts, offsets);
    k_fill  <<<(NTOK + 255) / 256, 256, 0, stream>>>(idx, wts, offsets, cursors, tok, wgt);

    dim3 gup(CAPTOT / BMT, EFF / BMT);       // (136, 4); inactive tiles early-exit
    k_up<<<gup, 256, 0, stream>>>(xh, xm, xl, uh, um, ul, offsets, tok, spk);

    dim3 gdn(CAPTOT / BMT, DMODEL / BMT);    // (136, 8)
    k_dn<<<gdn, 256, 0, stream>>>(spk, dh, dm, dl, offsets, tok, wgt, out);
}

// Round 6
// 1204.909 us; speedup vs baseline: 1.3709x; 1.3709x over previous
//
#include <hip/hip_runtime.h>
#include <stdint.h>

#define T_STEPS 4
#define NTOK    8192
#define DMODEL  1024
#define NEXP    8
#define EFF     512
#define BMT     128
#define CAPTOT  (2*NTOK + NEXP*BMT)   // 17408 assignment slots (regions padded to 128)

typedef __attribute__((ext_vector_type(8))) short bf8_t;   // 8 bf16 = one MFMA operand
typedef __attribute__((ext_vector_type(4))) float f32x4;   // MFMA accumulator

#define MFMA(a,b,c) __builtin_amdgcn_mfma_f32_16x16x32_bf16((a),(b),(c),0,0,0)

// ---------------- ws layout (bytes) ----------------
#define WS_TOK   128
#define WS_WGT   (WS_TOK + CAPTOT*4)
#define WS_SPK   (WS_WGT + CAPTOT*4)                  // bf16 spikes [t][CAPTOT][EFF]
#define SPK_SZ   ((size_t)4*CAPTOT*EFF*2)
#define WS_XH    (WS_SPK + SPK_SZ)
#define XPL_SZ   ((size_t)T_STEPS*NTOK*DMODEL*2)
#define WS_XM    (WS_XH + XPL_SZ)
#define WS_XL    (WS_XM + XPL_SZ)
#define WPL_SZ   ((size_t)NEXP*EFF*DMODEL*2)
#define WS_UH    (WS_XL + XPL_SZ)
#define WS_UM    (WS_UH + WPL_SZ)
#define WS_UL    (WS_UM + WPL_SZ)
#define WS_DH    (WS_UL + WPL_SZ)
#define WS_DM    (WS_DH + WPL_SZ)
#define WS_DL    (WS_DM + WPL_SZ)
// total ~309 MB (proven to fit in R5)

// ---------------- bf16 split helpers ----------------

__device__ __forceinline__ unsigned short bf16rn(float f) {
    unsigned u = __float_as_uint(f);
    unsigned r = u + 0x7fffu + ((u >> 16) & 1u);   // RNE
    return (unsigned short)(r >> 16);
}
__device__ __forceinline__ float bf2f(unsigned short h) {
    return __uint_as_float(((unsigned)h) << 16);
}
__device__ __forceinline__ unsigned pk(unsigned short a, unsigned short b) {
    return (unsigned)a | ((unsigned)b << 16);
}

// fp32 -> 3 bf16 limb planes, 8 elements per thread (memory-bound)
__global__ __launch_bounds__(256)
void k_split3(const float* __restrict__ in, unsigned short* __restrict__ ph,
              unsigned short* __restrict__ pm, unsigned short* __restrict__ pl, int n8) {
    int i = blockIdx.x * blockDim.x + threadIdx.x;
    if (i >= n8) return;
    const float* src = in + (size_t)i * 8;
    float v[8];
    *(float4*)&v[0] = *(const float4*)(src + 0);
    *(float4*)&v[4] = *(const float4*)(src + 4);
    unsigned short h[8], m[8], l[8];
#pragma unroll
    for (int j = 0; j < 8; ++j) {
        unsigned short a = bf16rn(v[j]);
        float r1 = v[j] - bf2f(a);
        unsigned short b = bf16rn(r1);
        float r2 = r1 - bf2f(b);
        h[j] = a; m[j] = b; l[j] = bf16rn(r2);
    }
    *(uint4*)(ph + (size_t)i*8) = make_uint4(pk(h[0],h[1]), pk(h[2],h[3]), pk(h[4],h[5]), pk(h[6],h[7]));
    *(uint4*)(pm + (size_t)i*8) = make_uint4(pk(m[0],m[1]), pk(m[2],m[3]), pk(m[4],m[5]), pk(m[6],m[7]));
    *(uint4*)(pl + (size_t)i*8) = make_uint4(pk(l[0],l[1]), pk(l[2],l[3]), pk(l[4],l[5]), pk(l[6],l[7]));
}

// ---------------- routing ----------------

__global__ void k_count(const int* __restrict__ idx, int* __restrict__ counts) {
    int n = blockIdx.x * blockDim.x + threadIdx.x;
    if (n >= NTOK) return;
    int e0 = idx[2*n], e1 = idx[2*n+1];
    atomicAdd(&counts[e0], 1);
    if (e1 != e0) atomicAdd(&counts[e1], 1);
}

__global__ void k_prefix(const int* __restrict__ counts, int* __restrict__ offsets) {
    if (threadIdx.x == 0) {
        int o = 0;
        for (int e = 0; e < NEXP; ++e) {
            offsets[e] = o;
            o += (counts[e] + BMT - 1) / BMT * BMT;
        }
        offsets[NEXP] = o;
    }
}

__global__ void k_fill(const int* __restrict__ idx, const float* __restrict__ wts,
                       const int* __restrict__ offsets, int* __restrict__ cursors,
                       int* __restrict__ tok, float* __restrict__ wgt) {
    int n = blockIdx.x * blockDim.x + threadIdx.x;
    if (n >= NTOK) return;
    int e0 = idx[2*n], e1 = idx[2*n+1];
    float w0 = wts[2*n], w1 = wts[2*n+1];
    if (e0 == e1) w0 = __fadd_rn(w0, w1);
    int p0 = offsets[e0] + atomicAdd(&cursors[e0], 1);
    tok[p0] = n; wgt[p0] = w0;
    if (e1 != e0) {
        int p1 = offsets[e1] + atomicAdd(&cursors[e1], 1);
        tok[p1] = n; wgt[p1] = w1;
    }
}

// ---------------- up-proj: LDS-tiled 3-limb bf16 MFMA + fused LIF -> bf16 spikes ----------------
// Block 128x128, 4 waves 2x2, wave-tile 64x64 (4x4 of 16x16x32). Staging = pure vector copy
// from presplit limb planes. 6 limb products. Membrane in registers, t-loop outer.

__global__ __launch_bounds__(256, 2)
void k_up(const unsigned short* __restrict__ xh, const unsigned short* __restrict__ xm,
          const unsigned short* __restrict__ xl, const unsigned short* __restrict__ wh,
          const unsigned short* __restrict__ wm, const unsigned short* __restrict__ wl,
          const int* __restrict__ offsets, const int* __restrict__ tok,
          unsigned short* __restrict__ spk) {
    const int m0 = blockIdx.x * BMT;
    const int ft = blockIdx.y;
    if (m0 >= offsets[NEXP]) return;
    int e = 0;
    for (int i = 1; i < NEXP; ++i) if (m0 >= offsets[i]) e = i;

    __shared__ unsigned short As[3][128][40];   // [limb][token][k], 80B stride -> free 2-way
    __shared__ unsigned short Bs[3][128][40];   // [limb][feature][k]

    const int tid  = threadIdx.x;
    const int lane = tid & 63, wid = tid >> 6;
    const int quad = lane >> 4, l16 = lane & 15;
    const int mw = (wid & 1) * 64, nw = (wid >> 1) * 64;

    // staging: thread -> row r (0..127), 16-elem half (two uint4 per plane-side)
    const int r = tid >> 1, half = tid & 1;
    const size_t arow = (size_t)tok[m0 + r] * DMODEL + half * 16;
    const size_t brow = ((size_t)e * EFF + ft * BMT + r) * DMODEL + half * 16;

    f32x4 mem[4][4];
#pragma unroll
    for (int i = 0; i < 4; ++i)
#pragma unroll
        for (int j = 0; j < 4; ++j) mem[i][j] = (f32x4){0.f,0.f,0.f,0.f};

    for (int t = 0; t < T_STEPS; ++t) {
        f32x4 acc[4][4];
#pragma unroll
        for (int i = 0; i < 4; ++i)
#pragma unroll
            for (int j = 0; j < 4; ++j) acc[i][j] = (f32x4){0.f,0.f,0.f,0.f};

        const size_t at = arow + (size_t)t * (NTOK * DMODEL);

        for (int kc = 0; kc < DMODEL; kc += 32) {
            __syncthreads();
            const int c = half * 16;
            *(uint4*)&As[0][r][c]   = *(const uint4*)(xh + at + kc);
            *(uint4*)&As[0][r][c+8] = *(const uint4*)(xh + at + kc + 8);
            *(uint4*)&As[1][r][c]   = *(const uint4*)(xm + at + kc);
            *(uint4*)&As[1][r][c+8] = *(const uint4*)(xm + at + kc + 8);
            *(uint4*)&As[2][r][c]   = *(const uint4*)(xl + at + kc);
            *(uint4*)&As[2][r][c+8] = *(const uint4*)(xl + at + kc + 8);
            *(uint4*)&Bs[0][r][c]   = *(const uint4*)(wh + brow + kc);
            *(uint4*)&Bs[0][r][c+8] = *(const uint4*)(wh + brow + kc + 8);
            *(uint4*)&Bs[1][r][c]   = *(const uint4*)(wm + brow + kc);
            *(uint4*)&Bs[1][r][c+8] = *(const uint4*)(wm + brow + kc + 8);
            *(uint4*)&Bs[2][r][c]   = *(const uint4*)(wl + brow + kc);
            *(uint4*)&Bs[2][r][c+8] = *(const uint4*)(wl + brow + kc + 8);
            __syncthreads();

            bf8_t bh[4], bm[4], bl[4];
#pragma unroll
            for (int nt = 0; nt < 4; ++nt) {
                const int nr = nw + nt*16 + l16;
                bh[nt] = *(const bf8_t*)&Bs[0][nr][quad*8];
                bm[nt] = *(const bf8_t*)&Bs[1][nr][quad*8];
                bl[nt] = *(const bf8_t*)&Bs[2][nr][quad*8];
            }
#pragma unroll
            for (int mt = 0; mt < 4; ++mt) {
                const int mr = mw + mt*16 + l16;
                bf8_t ah = *(const bf8_t*)&As[0][mr][quad*8];
                bf8_t am = *(const bf8_t*)&As[1][mr][quad*8];
                bf8_t al = *(const bf8_t*)&As[2][mr][quad*8];
#pragma unroll
                for (int nt = 0; nt < 4; ++nt) {
                    f32x4 c2 = acc[mt][nt];
                    c2 = MFMA(ah, bh[nt], c2);
                    c2 = MFMA(am, bh[nt], c2);
                    c2 = MFMA(ah, bm[nt], c2);
                    c2 = MFMA(am, bm[nt], c2);
                    c2 = MFMA(al, bh[nt], c2);
                    c2 = MFMA(ah, bl[nt], c2);
                    acc[mt][nt] = c2;
                }
            }
        }

        // fused LIF epilogue (C layout: row = quad*4+reg, col = l16)
#pragma unroll
        for (int mt = 0; mt < 4; ++mt)
#pragma unroll
            for (int nt = 0; nt < 4; ++nt)
#pragma unroll
                for (int reg = 0; reg < 4; ++reg) {
                    float mv = __fadd_rn(__fmul_rn(0.9f, mem[mt][nt][reg]), acc[mt][nt][reg]);
                    bool s = mv > 1.0f;
                    mem[mt][nt][reg] = __fsub_rn(mv, s ? 1.0f : 0.0f);
                    int row = m0 + mw + mt*16 + quad*4 + reg;
                    int col = ft*BMT + nw + nt*16 + l16;
                    spk[((size_t)t * CAPTOT + row) * EFF + col] = s ? 0x3F80u : 0u;
                }
    }
}

// ---------------- down-proj: exact bf16 spikes x 3-limb weights (LDS-tiled) + LIF + scatter ----
// Block 128x128, wave-tile 64x64 (4x4 tiles), K=EFF in 32-chunks, 3 products.

__global__ __launch_bounds__(256, 2)
void k_dn(const unsigned short* __restrict__ spk, const unsigned short* __restrict__ dh,
          const unsigned short* __restrict__ dm, const unsigned short* __restrict__ dl,
          const int* __restrict__ offsets, const int* __restrict__ tok,
          const float* __restrict__ wgt, float* __restrict__ out) {
    const int m0 = blockIdx.x * BMT;
    const int dt = blockIdx.y;
    if (m0 >= offsets[NEXP]) return;
    int e = 0;
    for (int i = 1; i < NEXP; ++i) if (m0 >= offsets[i]) e = i;

    __shared__ unsigned short As[128][40];      // spikes [token][k(f)]
    __shared__ unsigned short Bs[3][128][40];   // weights [limb][d][k(f)]

    const int tid  = threadIdx.x;
    const int lane = tid & 63, wid = tid >> 6;
    const int quad = lane >> 4, l16 = lane & 15;
    const int mw = (wid & 1) * 64, nw = (wid >> 1) * 64;

    const int r = tid >> 1, half = tid & 1;
    const size_t arow = (size_t)(m0 + r) * EFF + half * 16;
    const size_t brow = ((size_t)e * DMODEL + dt * BMT + r) * EFF + half * 16;

    int   rn[4][4];
    float rw[4][4];
#pragma unroll
    for (int mt = 0; mt < 4; ++mt)
#pragma unroll
        for (int reg = 0; reg < 4; ++reg) {
            int rr = m0 + mw + mt*16 + quad*4 + reg;
            rn[mt][reg] = tok[rr];
            rw[mt][reg] = wgt[rr];
        }

    f32x4 mem[4][4];
#pragma unroll
    for (int i = 0; i < 4; ++i)
#pragma unroll
        for (int j = 0; j < 4; ++j) mem[i][j] = (f32x4){0.f,0.f,0.f,0.f};

    for (int t = 0; t < T_STEPS; ++t) {
        f32x4 acc[4][4];
#pragma unroll
        for (int i = 0; i < 4; ++i)
#pragma unroll
            for (int j = 0; j < 4; ++j) acc[i][j] = (f32x4){0.f,0.f,0.f,0.f};

        const size_t at = arow + (size_t)t * (CAPTOT * EFF);

        for (int kc = 0; kc < EFF; kc += 32) {
            __syncthreads();
            const int c = half * 16;
            *(uint4*)&As[r][c]      = *(const uint4*)(spk + at + kc);
            *(uint4*)&As[r][c+8]    = *(const uint4*)(spk + at + kc + 8);
            *(uint4*)&Bs[0][r][c]   = *(const uint4*)(dh + brow + kc);
            *(uint4*)&Bs[0][r][c+8] = *(const uint4*)(dh + brow + kc + 8);
            *(uint4*)&Bs[1][r][c]   = *(const uint4*)(dm + brow + kc);
            *(uint4*)&Bs[1][r][c+8] = *(const uint4*)(dm + brow + kc + 8);
            *(uint4*)&Bs[2][r][c]   = *(const uint4*)(dl + brow + kc);
            *(uint4*)&Bs[2][r][c+8] = *(const uint4*)(dl + brow + kc + 8);
            __syncthreads();

            bf8_t bh[4], bm[4], bl[4];
#pragma unroll
            for (int nt = 0; nt < 4; ++nt) {
                const int nr = nw + nt*16 + l16;
                bh[nt] = *(const bf8_t*)&Bs[0][nr][quad*8];
                bm[nt] = *(const bf8_t*)&Bs[1][nr][quad*8];
                bl[nt] = *(const bf8_t*)&Bs[2][nr][quad*8];
            }
#pragma unroll
            for (int mt = 0; mt < 4; ++mt) {
                const int mr = mw + mt*16 + l16;
                bf8_t a = *(const bf8_t*)&As[mr][quad*8];
#pragma unroll
                for (int nt = 0; nt < 4; ++nt) {
                    f32x4 c2 = acc[mt][nt];
                    c2 = MFMA(a, bh[nt], c2);
                    c2 = MFMA(a, bm[nt], c2);
                    c2 = MFMA(a, bl[nt], c2);
                    acc[mt][nt] = c2;
                }
            }
        }

        // fused LIF + weighted sparse scatter (output spikes rare -> few atomics)
#pragma unroll
        for (int mt = 0; mt < 4; ++mt)
#pragma unroll
            for (int nt = 0; nt < 4; ++nt)
#pragma unroll
                for (int reg = 0; reg < 4; ++reg) {
                    float mv = __fadd_rn(__fmul_rn(0.9f, mem[mt][nt][reg]), acc[mt][nt][reg]);
                    bool s = mv > 1.0f;
                    mem[mt][nt][reg] = __fsub_rn(mv, s ? 1.0f : 0.0f);
                    float w = rw[mt][reg];
                    if (s && w != 0.0f) {
                        int col = dt*BMT + nw + nt*16 + l16;
                        atomicAdd(out + ((size_t)t * NTOK + rn[mt][reg]) * DMODEL + col, w);
                    }
                }
    }
}

// ---------------- launch ----------------

extern "C" void kernel_launch(void* const* d_in, const int* in_sizes, int n_in,
                              void* d_out, int out_size, void* d_ws, size_t ws_size,
                              hipStream_t stream) {
    const float* x      = (const float*)d_in[0];
    const int*   idx    = (const int*)  d_in[1];
    const float* wts    = (const float*)d_in[2];
    const float* up_w   = (const float*)d_in[3];
    const float* down_w = (const float*)d_in[4];
    float* out = (float*)d_out;

    char* ws = (char*)d_ws;
    int*   counts  = (int*)(ws + 0);
    int*   cursors = (int*)(ws + 32);
    int*   offsets = (int*)(ws + 64);
    int*   tok     = (int*)(ws + WS_TOK);
    float* wgt     = (float*)(ws + WS_WGT);
    unsigned short* spk = (unsigned short*)(ws + WS_SPK);
    unsigned short* xh = (unsigned short*)(ws + WS_XH);
    unsigned short* xm = (unsigned short*)(ws + WS_XM);
    unsigned short* xl = (unsigned short*)(ws + WS_XL);
    unsigned short* uh = (unsigned short*)(ws + WS_UH);
    unsigned short* um = (unsigned short*)(ws + WS_UM);
    unsigned short* ul = (unsigned short*)(ws + WS_UL);
    unsigned short* dh = (unsigned short*)(ws + WS_DH);
    unsigned short* dm = (unsigned short*)(ws + WS_DM);
    unsigned short* dl = (unsigned short*)(ws + WS_DL);

    hipMemsetAsync(ws, 0, WS_SPK, stream);                               // hdr + tok + wgt
    hipMemsetAsync(out, 0, (size_t)out_size * sizeof(float), stream);

    // presplit limb planes (memory-bound, ~80 us)
    const int nx8 = T_STEPS*NTOK*DMODEL/8;   // 4194304
    const int nw8 = NEXP*EFF*DMODEL/8;       // 524288
    k_split3<<<nx8/256, 256, 0, stream>>>(x, xh, xm, xl, nx8);
    k_split3<<<nw8/256, 256, 0, stream>>>(up_w, uh, um, ul, nw8);
    k_split3<<<nw8/256, 256, 0, stream>>>(down_w, dh, dm, dl, nw8);

    // routing
    k_count <<<(NTOK + 255) / 256, 256, 0, stream>>>(idx, counts);
    k_prefix<<<1, 64, 0, stream>>>(counts, offsets);
    k_fill  <<<(NTOK + 255) / 256, 256, 0, stream>>>(idx, wts, offsets, cursors, tok, wgt);

    dim3 gup(CAPTOT / BMT, EFF / BMT);       // (136, 4); inactive tiles early-exit
    k_up<<<gup, 256, 0, stream>>>(xh, xm, xl, uh, um, ul, offsets, tok, spk);

    dim3 gdn(CAPTOT / BMT, DMODEL / BMT);    // (136, 8)
    k_dn<<<gdn, 256, 0, stream>>>(spk, dh, dm, dl, offsets, tok, wgt, out);
}